// Round 5
// baseline (532.445 us; speedup 1.0000x reference)
//
#include <hip/hip_runtime.h>
#include <math.h>

// Problem constants (from reference)
#define BATCH 64
#define TDIM 512
#define FEAT 2048
#define HID 1024
#define KDIM 512
#define MROWS (BATCH * TDIM)  // 32768 flat feats rows
#define TCH 16                // k4 time-chunks
#define TCLEN (TDIM / TCH)    // 32 t per chunk

#define NSTEP (FEAT / 64)     // 32 K-tiles (BK=64)
#define TSLOT 2048            // 16B slots per 256x64 bf16 tile
#define ASLOTS (128 * 32 * TSLOT)  // 8,388,608 slots in packed A
#define BSLOTS (2 * 32 * TSLOT)    // 131,072 slots in packed B

typedef __attribute__((ext_vector_type(8))) short short8;
typedef __attribute__((ext_vector_type(4))) float floatx4;

// global -> LDS direct DMA, 16B per lane; LDS dest is wave-uniform base,
// lane i lands at base + i*16. Global source IS per-lane.
#define GLL16(g, l)                                                     \
    __builtin_amdgcn_global_load_lds(                                   \
        (const __attribute__((address_space(1))) void*)(g),             \
        (__attribute__((address_space(3))) void*)(l), 16, 0, 0)

#define VMWAIT(N) asm volatile("s_waitcnt vmcnt(" #N ")" ::: "memory")
#define SCHEDB    __builtin_amdgcn_sched_barrier(0)
#define SBAR      __builtin_amdgcn_s_barrier()

// ---------------------------------------------------------------------------
// f32 -> bf16 (round-to-nearest-even)
// ---------------------------------------------------------------------------
__device__ __forceinline__ unsigned short f2bf(float x) {
    unsigned int u = __float_as_uint(x);
    u += 0x7FFFu + ((u >> 16) & 1u);
    return (unsigned short)(u >> 16);
}

// ---------------------------------------------------------------------------
// k0p: blocks [0,8192): pack feats f32 -> bf16, layout [strip128][tile32]
//        [slot2048]; slot s of a tile holds row r=s>>3 (0..255), logical
//        chunk c=(s&7)^(r&7), i.e. feats[strip*256+r][tile*64+c*8 .. +8].
//        Reads 256B-contiguous per row, writes perfectly linear.
//      blocks [8192,8704): same pack for U -> [colBlock2][tile32][slot2048].
//      blocks [8704,16896): Whb[b,k] = hidden[b]·W[k] + bias[k].
// ---------------------------------------------------------------------------
__global__ __launch_bounds__(256) void k0p(const float* __restrict__ feats,
                                           const float* __restrict__ U,
                                           const float* __restrict__ hidden,
                                           const float* __restrict__ W,
                                           const float* __restrict__ bias,
                                           unsigned short* __restrict__ Apk,
                                           unsigned short* __restrict__ Bpk,
                                           float* __restrict__ whb) {
    int bx = blockIdx.x;
    if (bx < 8192) {
        for (size_t gsl = (size_t)bx * 256 + threadIdx.x; gsl < ASLOTS;
             gsl += (size_t)8192 * 256) {
            int strip = (int)(gsl >> 16);        // 65536 slots per strip
            int rem   = (int)(gsl & 65535);
            int tile  = rem >> 11;
            int s     = rem & 2047;
            int r     = s >> 3;
            int c     = (s & 7) ^ (r & 7);
            const float* src = feats + ((size_t)strip * 256 + r) * FEAT + tile * 64 + c * 8;
            float4 v0 = *(const float4*)src;
            float4 v1 = *(const float4*)(src + 4);
            ushort4 o0, o1;
            o0.x = f2bf(v0.x); o0.y = f2bf(v0.y); o0.z = f2bf(v0.z); o0.w = f2bf(v0.w);
            o1.x = f2bf(v1.x); o1.y = f2bf(v1.y); o1.z = f2bf(v1.z); o1.w = f2bf(v1.w);
            ((ushort4*)Apk)[gsl * 2]     = o0;
            ((ushort4*)Apk)[gsl * 2 + 1] = o1;
        }
    } else if (bx < 8704) {
        size_t gsl = (size_t)(bx - 8192) * 256 + threadIdx.x;  // exactly BSLOTS threads
        int cb   = (int)(gsl >> 16);
        int rem  = (int)(gsl & 65535);
        int tile = rem >> 11;
        int s    = rem & 2047;
        int r    = s >> 3;
        int c    = (s & 7) ^ (r & 7);
        const float* src = U + ((size_t)cb * 256 + r) * FEAT + tile * 64 + c * 8;
        float4 v0 = *(const float4*)src;
        float4 v1 = *(const float4*)(src + 4);
        ushort4 o0, o1;
        o0.x = f2bf(v0.x); o0.y = f2bf(v0.y); o0.z = f2bf(v0.z); o0.w = f2bf(v0.w);
        o1.x = f2bf(v1.x); o1.y = f2bf(v1.y); o1.z = f2bf(v1.z); o1.w = f2bf(v1.w);
        ((ushort4*)Bpk)[gsl * 2]     = o0;
        ((ushort4*)Bpk)[gsl * 2 + 1] = o1;
    } else {
        int bid = bx - 8704;                 // 0..8191
        int b = bid >> 7;                    // 0..63
        int k = (bid & 127) * 4 + (threadIdx.x >> 6);
        int lane = threadIdx.x & 63;
        const float* hrow = hidden + (size_t)b * HID;
        const float* wrow = W + (size_t)k * HID;
        float acc = 0.f;
        #pragma unroll 4
        for (int h = lane; h < HID; h += 64) acc += hrow[h] * wrow[h];
        #pragma unroll
        for (int off = 32; off > 0; off >>= 1) acc += __shfl_down(acc, off, 64);
        if (lane == 0) whb[b * KDIM + k] = acc + bias[k];
    }
}

// ---------------------------------------------------------------------------
// k2p: 256x256 8-phase bf16 MFMA GEMM (learn_hip m201 structure, plain HIP)
// + fused tanh/dot(w) epilogue -> partial energies (2 k-column blocks).
// 512 thr = 8 waves (2m x 4n); per-wave output 128x64 -> acc[8][4] f32x4.
// Per K-tile (BK=64): 4 phases x {stage 1 half-tile (2 GLL16) ; [vmcnt(2) at
// phase0] ; s_barrier ; ds_read af[4] (+bf[8] at phase0) ; setprio(1) ;
// 16 MFMA ; setprio(0) ; s_barrier}. Stage(t+1) -> buf[(t+1)&1] while
// computing buf[t&1]: buffers strictly disjoint; vmcnt(2) before bar1
// guarantees all waves' tile-t stages landed (the 2 left flying are the
// just-issued t+1.h0). No vmcnt(0) except the final tile. LDS 128 KiB ->
// 1 block/CU; grid (128,2) = 256 = #CUs. A and B both read from the k0p
// pack: every GLL16 is a contiguous 1 KB burst; XOR swizzle baked into the
// pack, read at phys = (kk*4+quad)^(col&7) (proven: 0 bank conflicts).
// ---------------------------------------------------------------------------
__global__ __launch_bounds__(512, 2) void k2p(const unsigned short* __restrict__ Apk,
                                              const unsigned short* __restrict__ Bpk,
                                              const float* __restrict__ whb,
                                              const float* __restrict__ wvec,
                                              float* __restrict__ partial) {
    __shared__ __align__(16) unsigned short As[2][16384];  // 2 x 32 KB
    __shared__ __align__(16) unsigned short Bs[2][16384];  // 2 x 32 KB

    const int tid  = threadIdx.x;
    const int wave = tid >> 6;
    const int lane = tid & 63;
    const int wm = wave >> 2, wn = wave & 3;
    const int col = lane & 15, quad = lane >> 4;
    const int bx = blockIdx.x, by = blockIdx.y;

    const unsigned short* gA = Apk + (size_t)bx * (32 * TSLOT) * 8;
    const unsigned short* gB = Bpk + (size_t)by * (32 * TSLOT) * 8;

    // stage half hh (0=A.h0,1=A.h1,2=B.h0,3=B.h1) of tile tt into buffer bb
    #define STAGE(tt, hh, bb)                                                   \
        do {                                                                    \
            const int sbase_ = ((hh) & 1) * 1024 + wave * 128;                  \
            if ((hh) < 2) {                                                     \
                GLL16(gA + ((size_t)(tt) * TSLOT + sbase_) * 8 + lane * 8,      \
                      &As[bb][sbase_ * 8]);                                     \
                GLL16(gA + ((size_t)(tt) * TSLOT + sbase_ + 64) * 8 + lane * 8, \
                      &As[bb][(sbase_ + 64) * 8]);                              \
            } else {                                                            \
                GLL16(gB + ((size_t)(tt) * TSLOT + sbase_) * 8 + lane * 8,      \
                      &Bs[bb][sbase_ * 8]);                                     \
                GLL16(gB + ((size_t)(tt) * TSLOT + sbase_ + 64) * 8 + lane * 8, \
                      &Bs[bb][(sbase_ + 64) * 8]);                              \
            }                                                                   \
        } while (0)

    floatx4 acc[8][4];
    #pragma unroll
    for (int i = 0; i < 8; ++i)
        #pragma unroll
        for (int j = 0; j < 4; ++j) acc[i][j] = (floatx4){0.f, 0.f, 0.f, 0.f};

    // prologue: tile 0's four halves into buf 0 (8 loads in flight)
    #pragma unroll
    for (int h = 0; h < 4; ++h) STAGE(0, h, 0);

    short8 bf[4][2];
    for (int t = 0; t < NSTEP; ++t) {
        const int cb = t & 1, sb = cb ^ 1;
        #pragma unroll
        for (int p = 0; p < 4; ++p) {
            if (t < NSTEP - 1) STAGE(t + 1, p, sb);
            if (p == 0) {
                if (t < NSTEP - 1) { VMWAIT(2); } else { VMWAIT(0); }
                SCHEDB;
            }
            SBAR; SCHEDB;  // bar1: tile t fully staged+visible for all waves

            short8 af[2][2];
            #pragma unroll
            for (int i = 0; i < 2; ++i)
                #pragma unroll
                for (int kk = 0; kk < 2; ++kk) {
                    const int row = wm * 128 + (2 * p + i) * 16 + col;
                    af[i][kk] = *(const short8*)
                        &As[cb][(row * 8 + ((kk * 4 + quad) ^ (col & 7))) * 8];
                }
            if (p == 0) {
                #pragma unroll
                for (int j = 0; j < 4; ++j)
                    #pragma unroll
                    for (int kk = 0; kk < 2; ++kk) {
                        const int row = wn * 64 + j * 16 + col;
                        bf[j][kk] = *(const short8*)
                            &Bs[cb][(row * 8 + ((kk * 4 + quad) ^ (col & 7))) * 8];
                    }
            }
            __builtin_amdgcn_s_setprio(1);
            #pragma unroll
            for (int i = 0; i < 2; ++i)
                #pragma unroll
                for (int j = 0; j < 4; ++j)
                    #pragma unroll
                    for (int kk = 0; kk < 2; ++kk)
                        acc[2 * p + i][j] = __builtin_amdgcn_mfma_f32_16x16x32_bf16(
                            af[i][kk], bf[j][kk], acc[2 * p + i][j], 0, 0, 0);
            __builtin_amdgcn_s_setprio(0);
            SCHEDB; SBAR; SCHEDB;  // bar2: compute(p) done, release next stage
        }
    }
    #undef STAGE

    __syncthreads();  // full drain; As now dead -> alias for epilogue sums

    float (*sums)[256] = (float (*)[256])As;
    const int b = bx >> 1;  // 256-row block = half a batch (T=512)
    float wk[4], hk[4];
    #pragma unroll
    for (int j = 0; j < 4; ++j) {
        const int k = by * 256 + wn * 64 + j * 16 + col;
        wk[j] = wvec[k];
        hk[j] = whb[b * KDIM + k];
    }
    #pragma unroll
    for (int i = 0; i < 8; ++i) {
        #pragma unroll
        for (int r = 0; r < 4; ++r) {
            float s = 0.f;
            #pragma unroll
            for (int j = 0; j < 4; ++j)
                s += tanhf(acc[i][j][r] + hk[j]) * wk[j];
            #pragma unroll
            for (int off = 8; off > 0; off >>= 1)
                s += __shfl_down(s, off, 16);
            if (col == 0)
                sums[wn][wm * 128 + i * 16 + quad * 4 + r] = s;
        }
    }
    __syncthreads();
    if (tid < 256)
        partial[(size_t)by * MROWS + bx * 256 + tid] =
            sums[0][tid] + sums[1][tid] + sums[2][tid] + sums[3][tid];
}

// ---------------------------------------------------------------------------
// k3n: energies = sum of 2 k-block partials; softmax over T per batch
// ---------------------------------------------------------------------------
__global__ __launch_bounds__(512) void k3n(const float* __restrict__ partial,
                                           float* __restrict__ wout) {
    int b = blockIdx.x;
    int t = threadIdx.x;
    int idx = b * TDIM + t;
    float e = partial[idx] + partial[MROWS + idx];

    __shared__ float sm[512];
    sm[t] = e;
    __syncthreads();
    #pragma unroll
    for (int s = 256; s > 0; s >>= 1) {
        if (t < s) sm[t] = fmaxf(sm[t], sm[t + s]);
        __syncthreads();
    }
    float m = sm[0];
    __syncthreads();
    float ex = __expf(e - m);
    sm[t] = ex;
    __syncthreads();
    #pragma unroll
    for (int s = 256; s > 0; s >>= 1) {
        if (t < s) sm[t] += sm[t + s];
        __syncthreads();
    }
    float inv = 1.f / sm[0];
    wout[b * TDIM + t] = ex * inv;
}

// ---------------------------------------------------------------------------
// k4p: T-chunked weighted pooling from the PACKED bf16 feats (half the f32
// traffic). Thread owns one 8-col chunk: tile=tid>>3, ch=tid&7; per row r
// the chunk sits at phys = ch^(r&7). grid (TCH=16, BATCH).
// ---------------------------------------------------------------------------
__global__ __launch_bounds__(256) void k4p(const unsigned short* __restrict__ Apk,
                                           const float* __restrict__ weights,
                                           float* __restrict__ partial4) {
    int b  = blockIdx.y;
    int t0 = blockIdx.x * TCLEN;
    int tile = threadIdx.x >> 3;
    int ch   = threadIdx.x & 7;
    int f0   = tile * 64 + ch * 8;
    __shared__ float wsm[TCLEN];
    if (threadIdx.x < TCLEN) wsm[threadIdx.x] = weights[b * TDIM + t0 + threadIdx.x];
    __syncthreads();

    float a[8];
    #pragma unroll
    for (int e = 0; e < 8; ++e) a[e] = 0.f;
    #pragma unroll 4
    for (int t = 0; t < TCLEN; ++t) {
        int row = b * TDIM + t0 + t;
        int strip = row >> 8, r = row & 255;
        const short8 v = *(const short8*)(Apk +
            (((size_t)strip * 65536 + (size_t)tile * TSLOT + r * 8 + (ch ^ (r & 7))) * 8));
        float w = wsm[t];
        #pragma unroll
        for (int e = 0; e < 8; ++e)
            a[e] += __uint_as_float(((unsigned int)(unsigned short)v[e]) << 16) * w;
    }
    float* op = partial4 + ((size_t)blockIdx.x * BATCH + b) * FEAT + f0;
    float4 o0 = {a[0], a[1], a[2], a[3]};
    float4 o1 = {a[4], a[5], a[6], a[7]};
    *(float4*)op = o0;
    *(float4*)(op + 4) = o1;
}

__global__ __launch_bounds__(256) void k5_reduce(const float* __restrict__ partial4,
                                                 float* __restrict__ out) {
    int i4 = blockIdx.x * 256 + threadIdx.x;  // float4 index into B*FEAT
    float4 s = ((const float4*)partial4)[i4];
    #pragma unroll
    for (int c = 1; c < TCH; ++c) {
        float4 v = ((const float4*)partial4)[(size_t)c * (BATCH * FEAT / 4) + i4];
        s.x += v.x; s.y += v.y; s.z += v.z; s.w += v.w;
    }
    ((float4*)out)[i4] = s;
}

// ---------------------------------------------------------------------------
// Fallback-path kernels (tiny ws): original k1 + f32 tile GEMM + direct pool
// ---------------------------------------------------------------------------
#define BM 128
#define BN 128
#define BF 16
#define LDSPAD 4

__global__ __launch_bounds__(256) void k1_whb(const float* __restrict__ hidden,
                                              const float* __restrict__ W,
                                              const float* __restrict__ bias,
                                              float* __restrict__ whb) {
    int b = blockIdx.y;
    int k = blockIdx.x * 4 + (threadIdx.x >> 6);
    int lane = threadIdx.x & 63;
    const float* hrow = hidden + (size_t)b * HID;
    const float* wrow = W + (size_t)k * HID;
    float acc = 0.f;
    #pragma unroll 4
    for (int h = lane; h < HID; h += 64) acc += hrow[h] * wrow[h];
    #pragma unroll
    for (int off = 32; off > 0; off >>= 1) acc += __shfl_down(acc, off, 64);
    if (lane == 0) whb[b * KDIM + k] = acc + bias[k];
}

__global__ __launch_bounds__(256) void k2_energy(const float* __restrict__ feats,
                                                 const float* __restrict__ U,
                                                 const float* __restrict__ whb,
                                                 const float* __restrict__ wvec,
                                                 float* __restrict__ partial) {
    __shared__ __align__(16) float As[BF][BM + LDSPAD];
    __shared__ __align__(16) float Us[BF][BN + LDSPAD];

    const int row0 = blockIdx.x * BM;
    const int k0   = blockIdx.y * BN;
    const int tid  = threadIdx.x;
    const int tx   = tid & 15;
    const int ty   = tid >> 4;

    float acc[8][8];
    #pragma unroll
    for (int i = 0; i < 8; ++i)
        #pragma unroll
        for (int j = 0; j < 8; ++j) acc[i][j] = 0.f;

    for (int f0 = 0; f0 < FEAT; f0 += BF) {
        #pragma unroll
        for (int l = 0; l < 2; ++l) {
            int li = tid + l * 256;
            int r  = li >> 2;
            int c4 = (li & 3) * 4;
            float4 av = *(const float4*)(feats + (size_t)(row0 + r) * FEAT + f0 + c4);
            float4 uv = *(const float4*)(U     + (size_t)(k0   + r) * FEAT + f0 + c4);
            As[c4 + 0][r] = av.x; As[c4 + 1][r] = av.y;
            As[c4 + 2][r] = av.z; As[c4 + 3][r] = av.w;
            Us[c4 + 0][r] = uv.x; Us[c4 + 1][r] = uv.y;
            Us[c4 + 2][r] = uv.z; Us[c4 + 3][r] = uv.w;
        }
        __syncthreads();
        #pragma unroll
        for (int kf = 0; kf < BF; ++kf) {
            float4 a0 = *(const float4*)&As[kf][ty * 8];
            float4 a1 = *(const float4*)&As[kf][ty * 8 + 4];
            float4 u0 = *(const float4*)&Us[kf][tx * 8];
            float4 u1 = *(const float4*)&Us[kf][tx * 8 + 4];
            float a[8] = {a0.x, a0.y, a0.z, a0.w, a1.x, a1.y, a1.z, a1.w};
            float u[8] = {u0.x, u0.y, u0.z, u0.w, u1.x, u1.y, u1.z, u1.w};
            #pragma unroll
            for (int i = 0; i < 8; ++i)
                #pragma unroll
                for (int j = 0; j < 8; ++j) acc[i][j] += a[i] * u[j];
        }
        __syncthreads();
    }

    const int b = row0 >> 9;
    float psum[8];
    #pragma unroll
    for (int i = 0; i < 8; ++i) {
        float s = 0.f;
        #pragma unroll
        for (int j = 0; j < 8; ++j) {
            int k = k0 + tx * 8 + j;
            s += tanhf(acc[i][j] + whb[b * KDIM + k]) * wvec[k];
        }
        psum[i] = s;
    }
    #pragma unroll
    for (int off = 8; off > 0; off >>= 1)
        #pragma unroll
        for (int i = 0; i < 8; ++i) psum[i] += __shfl_down(psum[i], off, 16);

    if (tx == 0) {
        int c = blockIdx.y;
        #pragma unroll
        for (int i = 0; i < 8; ++i)
            partial[c * MROWS + row0 + ty * 8 + i] = psum[i];
    }
}

__global__ __launch_bounds__(512) void k3_softmax(const float* __restrict__ partial,
                                                  float* __restrict__ wout) {
    int b = blockIdx.x;
    int t = threadIdx.x;
    float e = 0.f;
    #pragma unroll
    for (int c = 0; c < 4; ++c) e += partial[c * MROWS + b * TDIM + t];

    __shared__ float sm[512];
    sm[t] = e;
    __syncthreads();
    #pragma unroll
    for (int s = 256; s > 0; s >>= 1) {
        if (t < s) sm[t] = fmaxf(sm[t], sm[t + s]);
        __syncthreads();
    }
    float m = sm[0];
    __syncthreads();
    float ex = __expf(e - m);
    sm[t] = ex;
    __syncthreads();
    #pragma unroll
    for (int s = 256; s > 0; s >>= 1) {
        if (t < s) sm[t] += sm[t + s];
        __syncthreads();
    }
    float inv = 1.f / sm[0];
    wout[b * TDIM + t] = ex * inv;
}

__global__ __launch_bounds__(256) void k4_direct(const float* __restrict__ feats,
                                                 const float* __restrict__ weights,
                                                 float* __restrict__ out) {
    int b = blockIdx.y;
    int f4 = (blockIdx.x * 256 + threadIdx.x) * 4;
    __shared__ float wsm[TDIM];
    wsm[threadIdx.x]       = weights[b * TDIM + threadIdx.x];
    wsm[threadIdx.x + 256] = weights[b * TDIM + 256 + threadIdx.x];
    __syncthreads();

    const float* fp = feats + (size_t)b * TDIM * FEAT + f4;
    float ax = 0.f, ay = 0.f, az = 0.f, aw = 0.f;
    for (int t = 0; t < TDIM; ++t) {
        float4 v = *(const float4*)(fp + (size_t)t * FEAT);
        float w = wsm[t];
        ax += v.x * w; ay += v.y * w; az += v.z * w; aw += v.w * w;
    }
    float4 o = {ax, ay, az, aw};
    *(float4*)(out + (size_t)b * FEAT + f4) = o;
}

// ---------------------------------------------------------------------------
// Launch. d_out: [0, B*FEAT) attn_feats, [B*FEAT, +B*T) weights.
// d_out staging: Whb in weights region (dead after k2p); energy partials
// (2 x MROWS = 256 KB) in attn region (512 KB, dead after k3n).
// d_ws: packed bf16 A (128 MiB) + packed bf16 B (2 MiB) + pool partials
// (8 MiB). Branch on host-constant ws_size (graph-safe).
// ---------------------------------------------------------------------------
extern "C" void kernel_launch(void* const* d_in, const int* in_sizes, int n_in,
                              void* d_out, int out_size, void* d_ws, size_t ws_size,
                              hipStream_t stream) {
    const float* hidden = (const float*)d_in[0];
    const float* feats  = (const float*)d_in[1];
    const float* W      = (const float*)d_in[2];
    const float* U      = (const float*)d_in[3];
    const float* bias   = (const float*)d_in[4];
    const float* wvec   = (const float*)d_in[5];

    float* out         = (float*)d_out;
    float* attn_out    = out;
    float* weights_out = out + (size_t)BATCH * FEAT;
    float* whb         = weights_out;  // staged (dead after k2p)
    float* partial     = attn_out;     // staged (dead after k3n)

    const size_t aBytes    = (size_t)ASLOTS * 16;  // 128 MiB
    const size_t bBytes    = (size_t)BSLOTS * 16;  // 2 MiB
    const size_t poolBytes = (size_t)TCH * BATCH * FEAT * sizeof(float);
    const bool fast = ws_size >= aBytes + bBytes + poolBytes;

    if (fast) {
        unsigned short* Apk = (unsigned short*)d_ws;
        unsigned short* Bpk = (unsigned short*)((char*)d_ws + aBytes);
        float* pool4 = (float*)((char*)d_ws + aBytes + bBytes);
        k0p<<<dim3(16896), 256, 0, stream>>>(feats, U, hidden, W, bias,
                                             Apk, Bpk, whb);
        k2p<<<dim3(128, 2), 512, 0, stream>>>(Apk, Bpk, whb, wvec, partial);
        k3n<<<dim3(BATCH), 512, 0, stream>>>(partial, weights_out);
        k4p<<<dim3(TCH, BATCH), 256, 0, stream>>>(Apk, weights_out, pool4);
        k5_reduce<<<dim3(BATCH * FEAT / 4 / 256), 256, 0, stream>>>(pool4, attn_out);
    } else {
        k1_whb<<<dim3(KDIM / 4, BATCH), 256, 0, stream>>>(hidden, W, bias, whb);
        k2_energy<<<dim3(MROWS / 128, KDIM / 128), 256, 0, stream>>>(
            feats, U, whb, wvec, partial);
        k3_softmax<<<dim3(BATCH), 512, 0, stream>>>(partial, weights_out);
        k4_direct<<<dim3(FEAT / 1024, BATCH), 256, 0, stream>>>(
            feats, weights_out, attn_out);
    }
}